// Round 5
// baseline (398.748 us; speedup 1.0000x reference)
//
#include <hip/hip_runtime.h>
#include <math.h>

// ANI per-type MLP ensemble, MI355X bf16-MFMA.
// R5: barrier-free k_mlp. Wave = 32 atoms (2 M-tiles), private LDS strip per
//     wave (double-buffered X slices), ZERO __syncthreads -> compiler can
//     pipeline staging loads + B-fragment stream past MFMAs. B-frags shared
//     by 2 tiles (2:1 MFMA:load). Epilogue reduces acc2 in-register (shfl).
//     R4 lesson: occupancy (29->52%) changed nothing; stalls are structural.

#define NATOMS   131072                     // 2048 * 64
#define NMOL     2048
#define AEV      384
#define NTYPES   4
#define MBLK     128                        // atoms per MLP block (32/wave)
#define PADTOT   (NATOMS + NTYPES * MBLK)   // 131584 (buckets padded to 128)
#define NBLK_MLP (PADTOT / MBLK)            // 1028
#define NBLK_H   512                        // histogram blocks (256 atoms each)

// swizzled-weight layout (bf16, per type): L0 [12kt][10nt][64][8] = 61440,
// L1 [5][8][64][8] = 20480, L2 [4][6][64][8] = 12288  -> 94208 per type
#define WB_L1 61440
#define WB_L2 81920
#define WB_T  94208

typedef __attribute__((ext_vector_type(8))) short bf16x8;
typedef __attribute__((ext_vector_type(4))) float f32x4;
typedef unsigned short ushort;

__device__ __forceinline__ float celu01(float v) {
  return (v > 0.f) ? v : 0.1f * (__expf(v * 10.f) - 1.f);  // jax.nn.celu alpha=0.1
}
__device__ __forceinline__ ushort f2bf(float x) {  // RNE
  unsigned u = __float_as_uint(x);
  return (ushort)((u + 0x7FFFu + ((u >> 16) & 1u)) >> 16);
}

// ---- fused prep: out init + perm init + weight swizzle + histogram ----------

__global__ void k_pre(const int* __restrict__ species, float* __restrict__ out,
                      int* __restrict__ perm, int* __restrict__ hist,
                      const float* __restrict__ W0, const float* __restrict__ W1,
                      const float* __restrict__ W2, ushort* __restrict__ WB) {
  const int tid = threadIdx.x, blk = blockIdx.x;
  const int i = blk * 256 + tid;                  // grid = PADTOT/256 = 514
  perm[i] = -1;
  if (i < NATOMS) out[i] = (float)species[i];     // output 0: species passthrough
  if (i < NMOL) out[NATOMS + i] = 0.f;            // output 1: energies

  for (int f = i; f < NTYPES * WB_T; f += PADTOT) {   // weight swizzle
    const int t = f / WB_T, e0 = f - t * WB_T;
    int base, NT, N;
    const float* W;
    if (e0 < WB_L1)      { base = 0;     NT = 10; N = 160; W = W0 + (size_t)t * AEV * 160; }
    else if (e0 < WB_L2) { base = WB_L1; NT = 8;  N = 128; W = W1 + (size_t)t * 160 * 128; }
    else                 { base = WB_L2; NT = 6;  N = 96;  W = W2 + (size_t)t * 128 * 96; }
    const int e = e0 - base, frag = e >> 9, r = e & 511, lane = r >> 3, j = r & 7;
    const int kt = frag / NT, nt = frag - kt * NT;
    const int k = kt * 32 + ((lane >> 4) << 3) + j, n = nt * 16 + (lane & 15);
    WB[(size_t)t * WB_T + e0] = f2bf(W[k * N + n]);
  }

  if (blk < NBLK_H) {                             // histogram (blocks 0..511)
    const int sp = species[i];
    const int wv = tid >> 6;
    __shared__ int wc[4 * NTYPES];
#pragma unroll
    for (int t = 0; t < NTYPES; ++t) {
      const unsigned long long m = __ballot(sp == t);
      if ((tid & 63) == 0) wc[wv * NTYPES + t] = __popcll(m);
    }
    __syncthreads();
    if (tid < NTYPES)
      hist[tid * NBLK_H + blk] = wc[tid] + wc[4 + tid] + wc[8 + tid] + wc[12 + tid];
  }
}

// ---- scan + scatter (atomic-free counting sort) -----------------------------

__global__ void k_scan(const int* __restrict__ hist, int* __restrict__ poff,
                       int* __restrict__ boff) {
  __shared__ int tot[NTYPES], base[NTYPES];
  const int tid = threadIdx.x, wv = tid >> 6, lane = tid & 63;
  int s = 0;
  for (int c = 0; c < 8; ++c) s += hist[wv * NBLK_H + c * 64 + lane];
  for (int off = 32; off; off >>= 1) s += __shfl_down(s, off);
  if (lane == 0) tot[wv] = s;
  __syncthreads();
  if (tid == 0) {
    int acc = 0; poff[0] = 0;
    for (int t = 0; t < NTYPES; ++t) {
      base[t] = acc;
      acc += ((tot[t] + 127) >> 7) << 7;          // pad buckets to 128
      poff[t + 1] = acc;
    }
  }
  __syncthreads();
  int carry = base[wv];
  for (int c = 0; c < 8; ++c) {
    const int orig = hist[wv * NBLK_H + c * 64 + lane];
    int v = orig;
    for (int off = 1; off < 64; off <<= 1) {
      const int u = __shfl_up(v, off);
      if (lane >= off) v += u;
    }
    boff[wv * NBLK_H + c * 64 + lane] = carry + v - orig;
    carry += __shfl(v, 63);
  }
}

__global__ void k_scatter(const int* __restrict__ species, const int* __restrict__ boff,
                          int* __restrict__ perm) {
  const int tid = threadIdx.x, blk = blockIdx.x;
  const int i = blk * 256 + tid;
  const int sp = species[i];
  const int wv = tid >> 6;
  __shared__ int wc[4 * NTYPES];
  unsigned long long msel = 0;
#pragma unroll
  for (int t = 0; t < NTYPES; ++t) {
    const unsigned long long m = __ballot(sp == t);
    if ((tid & 63) == 0) wc[wv * NTYPES + t] = __popcll(m);
    if (sp == t) msel = m;
  }
  __syncthreads();
  int woff = 0;
  for (int w = 0; w < wv; ++w) woff += wc[w * NTYPES + sp];
  const int rk = __builtin_amdgcn_mbcnt_hi((unsigned)(msel >> 32),
                 __builtin_amdgcn_mbcnt_lo((unsigned)msel, 0));
  perm[boff[sp * NBLK_H + blk] + woff + rk] = i;
}

// ---- barrier-free 4-layer MFMA MLP + molecule reduction ---------------------
// 256 thr = 4 waves; wave owns 32 atoms = 2 M-tiles, private 10752B LDS strip:
//   X slices (64 cols, dbuf 2x32x72 ush) -> H0 32x168 -> H1 32x136.
// All strides give worst-case 2-way bank alias on ds_read_b128 (free, m136).

__global__ __launch_bounds__(256, 2) void k_mlp(
    const float* __restrict__ aev, const ushort* __restrict__ WB,
    const float* __restrict__ b0, const float* __restrict__ b1,
    const float* __restrict__ b2, const float* __restrict__ b3,
    const float* __restrict__ W3,
    const int* __restrict__ poff, const int* __restrict__ perm,
    float* __restrict__ outE)
{
  __shared__ __align__(16) ushort ARENA[4 * 5376];   // 43008 B, one strip/wave

  const int tid  = threadIdx.x;
  const int lane = tid & 63;
  const int wv   = __builtin_amdgcn_readfirstlane(tid >> 6);
  const int quad = lane >> 4, l15 = lane & 15;
  const int slot0 = blockIdx.x * MBLK;
  const int wbase = wv * 5376;

  int t_ = (slot0 >= poff[1]) + (slot0 >= poff[2]) + (slot0 >= poff[3]);
  if (t_ > 3) t_ = 3;
  const int t = __builtin_amdgcn_readfirstlane(t_);

  const bf16x8* wb0 = (const bf16x8*)(WB + (size_t)t * WB_T);
  const bf16x8* wb1 = (const bf16x8*)(WB + (size_t)t * WB_T + WB_L1);
  const bf16x8* wb2 = (const bf16x8*)(WB + (size_t)t * WB_T + WB_L2);

  // staging mapping: lane -> atom a = lane>>1 (0..31), col-half ch = lane&1
  const int a  = lane >> 1, ch = lane & 1;
  const int pa = perm[slot0 + wv * 32 + a];
  const float4* src = (const float4*)(aev + (size_t)(pa < 0 ? 0 : pa) * AEV);

  // ---------------- layer 0: 384 -> 160, 6 slices of 64 cols -----------------
  f32x4 acc0[10], acc1[10];
#pragma unroll
  for (int nt = 0; nt < 10; ++nt) {
    const float b = b0[t * 160 + nt * 16 + l15];
    acc0[nt] = (f32x4){b, b, b, b};
    acc1[nt] = (f32x4){b, b, b, b};
  }
#pragma unroll
  for (int s = 0; s < 6; ++s) {
    float4 f[8];
#pragma unroll
    for (int i = 0; i < 8; ++i) {
      f[i] = src[s * 16 + ch * 8 + i];
      if (pa < 0) f[i] = make_float4(0.f, 0.f, 0.f, 0.f);
    }
    const int wb = wbase + (s & 1) * 2304 + a * 72 + ch * 32;
#pragma unroll
    for (int i = 0; i < 4; ++i) {
      bf16x8 p = {(short)f2bf(f[2*i].x), (short)f2bf(f[2*i].y),
                  (short)f2bf(f[2*i].z), (short)f2bf(f[2*i].w),
                  (short)f2bf(f[2*i+1].x), (short)f2bf(f[2*i+1].y),
                  (short)f2bf(f[2*i+1].z), (short)f2bf(f[2*i+1].w)};
      *(bf16x8*)&ARENA[wb + i * 8] = p;
    }
#pragma unroll
    for (int k2 = 0; k2 < 2; ++k2) {
      const int rb = wbase + (s & 1) * 2304 + k2 * 32 + quad * 8;
      const bf16x8 a0 = *(const bf16x8*)&ARENA[rb + l15 * 72];
      const bf16x8 a1 = *(const bf16x8*)&ARENA[rb + (16 + l15) * 72];
      const int ksg = s * 2 + k2;
#pragma unroll
      for (int nt = 0; nt < 10; ++nt) {
        const bf16x8 bf = wb0[(ksg * 10 + nt) * 64 + lane];
        acc0[nt] = __builtin_amdgcn_mfma_f32_16x16x32_bf16(a0, bf, acc0[nt], 0, 0, 0);
        acc1[nt] = __builtin_amdgcn_mfma_f32_16x16x32_bf16(a1, bf, acc1[nt], 0, 0, 0);
      }
    }
  }
  // H0 pack: rows 32 x stride 168
#pragma unroll
  for (int nt = 0; nt < 10; ++nt)
#pragma unroll
    for (int r = 0; r < 4; ++r) {
      ARENA[wbase + (quad * 4 + r) * 168 + nt * 16 + l15]        = f2bf(celu01(acc0[nt][r]));
      ARENA[wbase + (16 + quad * 4 + r) * 168 + nt * 16 + l15]   = f2bf(celu01(acc1[nt][r]));
    }

  // ---------------- layer 1: 160 -> 128 --------------------------------------
  f32x4 accB0[8], accB1[8];
#pragma unroll
  for (int nt = 0; nt < 8; ++nt) {
    const float b = b1[t * 128 + nt * 16 + l15];
    accB0[nt] = (f32x4){b, b, b, b};
    accB1[nt] = (f32x4){b, b, b, b};
  }
#pragma unroll
  for (int ks = 0; ks < 5; ++ks) {
    const int rb = wbase + ks * 32 + quad * 8;
    const bf16x8 a0 = *(const bf16x8*)&ARENA[rb + l15 * 168];
    const bf16x8 a1 = *(const bf16x8*)&ARENA[rb + (16 + l15) * 168];
#pragma unroll
    for (int nt = 0; nt < 8; ++nt) {
      const bf16x8 bf = wb1[(ks * 8 + nt) * 64 + lane];
      accB0[nt] = __builtin_amdgcn_mfma_f32_16x16x32_bf16(a0, bf, accB0[nt], 0, 0, 0);
      accB1[nt] = __builtin_amdgcn_mfma_f32_16x16x32_bf16(a1, bf, accB1[nt], 0, 0, 0);
    }
  }
  // H1 pack: rows 32 x stride 136 (in-order DS pipe: safe vs pending H0 reads)
#pragma unroll
  for (int nt = 0; nt < 8; ++nt)
#pragma unroll
    for (int r = 0; r < 4; ++r) {
      ARENA[wbase + (quad * 4 + r) * 136 + nt * 16 + l15]      = f2bf(celu01(accB0[nt][r]));
      ARENA[wbase + (16 + quad * 4 + r) * 136 + nt * 16 + l15] = f2bf(celu01(accB1[nt][r]));
    }

  // ---------------- layer 2: 128 -> 96 ---------------------------------------
  f32x4 accC0[6], accC1[6];
#pragma unroll
  for (int nt = 0; nt < 6; ++nt) {
    const float b = b2[t * 96 + nt * 16 + l15];
    accC0[nt] = (f32x4){b, b, b, b};
    accC1[nt] = (f32x4){b, b, b, b};
  }
#pragma unroll
  for (int ks = 0; ks < 4; ++ks) {
    const int rb = wbase + ks * 32 + quad * 8;
    const bf16x8 a0 = *(const bf16x8*)&ARENA[rb + l15 * 136];
    const bf16x8 a1 = *(const bf16x8*)&ARENA[rb + (16 + l15) * 136];
#pragma unroll
    for (int nt = 0; nt < 6; ++nt) {
      const bf16x8 bf = wb2[(ks * 6 + nt) * 64 + lane];
      accC0[nt] = __builtin_amdgcn_mfma_f32_16x16x32_bf16(a0, bf, accC0[nt], 0, 0, 0);
      accC1[nt] = __builtin_amdgcn_mfma_f32_16x16x32_bf16(a1, bf, accC1[nt], 0, 0, 0);
    }
  }

  // ---------------- layer 3: 96 -> 1, in-register (C-layout) -----------------
  // C/D: col = l15, row = quad*4 + r. energy[row] = sum_cols celu(h2)*w3[col].
  float w3v[6];
#pragma unroll
  for (int nt = 0; nt < 6; ++nt) w3v[nt] = W3[t * 96 + nt * 16 + l15];
  const float b3t = b3[t];

  float pe[2][4];
#pragma unroll
  for (int m = 0; m < 2; ++m)
#pragma unroll
    for (int r = 0; r < 4; ++r) {
      float p = 0.f;
#pragma unroll
      for (int nt = 0; nt < 6; ++nt)
        p = fmaf(celu01(m ? accC1[nt][r] : accC0[nt][r]), w3v[nt], p);
      p += __shfl_xor(p, 1);     // butterfly over the 16-lane col group
      p += __shfl_xor(p, 2);
      p += __shfl_xor(p, 4);
      p += __shfl_xor(p, 8);
      pe[m][r] = p;
    }
  if (l15 == 0) {
#pragma unroll
    for (int m = 0; m < 2; ++m)
#pragma unroll
      for (int r = 0; r < 4; ++r) {
        const int ai = perm[slot0 + wv * 32 + m * 16 + quad * 4 + r];
        if (ai >= 0) atomicAdd(&outE[ai >> 6], pe[m][r] + b3t);
      }
  }
}

// ---- launch -----------------------------------------------------------------

extern "C" void kernel_launch(void* const* d_in, const int* in_sizes, int n_in,
                              void* d_out, int out_size, void* d_ws, size_t ws_size,
                              hipStream_t stream)
{
  const int*   species = (const int*)d_in[0];
  const float* aev     = (const float*)d_in[1];
  const float* W0 = (const float*)d_in[2];
  const float* b0 = (const float*)d_in[3];
  const float* W1 = (const float*)d_in[4];
  const float* b1 = (const float*)d_in[5];
  const float* W2 = (const float*)d_in[6];
  const float* b2 = (const float*)d_in[7];
  const float* W3 = (const float*)d_in[8];
  const float* b3 = (const float*)d_in[9];
  float* out = (float*)d_out;

  // ws (ints): poff[8], hist[2048], boff[2048], perm[PADTOT]; then bf16 WB
  int* poff = (int*)d_ws;
  int* hist = poff + 8;
  int* boff = hist + NTYPES * NBLK_H;
  int* perm = boff + NTYPES * NBLK_H;
  ushort* WB = (ushort*)(perm + PADTOT);

  k_pre    <<<PADTOT / 256, 256, 0, stream>>>(species, out, perm, hist, W0, W1, W2, WB);
  k_scan   <<<1, 256, 0, stream>>>(hist, poff, boff);
  k_scatter<<<NBLK_H, 256, 0, stream>>>(species, boff, perm);
  k_mlp    <<<NBLK_MLP, 256, 0, stream>>>(aev, WB, b0, b1, b2, b3, W3,
                                          poff, perm, out + NATOMS);
}